// Round 5
// baseline (157.120 us; speedup 1.0000x reference)
//
#include <hip/hip_runtime.h>

// ---------------- meta layout in d_ws, units of 4 bytes ----------------
#define M_SI    0      // f32[256] softmax max-prob per input channel
#define M_SO    256    // f32[256] per filter
#define M_CLIST 512    // i32[256] input channels, group-major stable
#define M_FLIST 768    // i32[256] filters, group-major stable (= perm)
#define M_DEST  1024   // i32[256] dest[f] = output channel for filter f
#define M_CBASE 1280   // i32[8]
#define M_FBASE 1288   // i32[8]
#define M_CCNT  1296   // i32[8]
#define M_FCNT  1304   // i32[8]
#define M_WOFFE 1312   // i32[9] element offsets into wpack, [8]=total
#define WPACK_BYTE_OFF 16384
#define XR_BYTE_OFF   (4u << 20)          // 4 MB
#define SLOT_ELEMS    3444736ull          // 32 b * 58*58 * 32 ch (bf16 elems)
#define SLOT_BYTES    (SLOT_ELEMS * 2ull)
#define CHX 40                            // 1KB x-chunks per phase (10 per wave)

typedef short bf16x8 __attribute__((ext_vector_type(8)));
typedef float f32x4  __attribute__((ext_vector_type(4)));

__device__ __forceinline__ unsigned short f2bf(float f) {
    unsigned u = __float_as_uint(f);
    u += 0x7fffu + ((u >> 16) & 1u);
    return (unsigned short)(u >> 16);
}

__device__ __forceinline__ void gl_lds16(const void* g, void* l) {
    __builtin_amdgcn_global_load_lds((const __attribute__((address_space(1))) unsigned int*)g,
                                     (__attribute__((address_space(3))) unsigned int*)l, 16, 0, 0);
}

__global__ __launch_bounds__(256) void flgc_setup(const float* __restrict__ S,
                                                  const float* __restrict__ T,
                                                  int* __restrict__ meta) {
    __shared__ float si[256], so[256];
    __shared__ int gin[256], gout[256];
    __shared__ int cnt_in[8], cnt_out[8], cb[8], fb[8];
    __shared__ int perm[256], destl[256];
    const int c = threadIdx.x;  // 0..255

    {   // softmax max-prob + argmax (first occurrence) for S row c
        float m = S[c * 8]; int am = 0;
        for (int k = 1; k < 8; ++k) { float v = S[c * 8 + k]; if (v > m) { m = v; am = k; } }
        float s = 0.f;
        for (int k = 0; k < 8; ++k) s += expf(S[c * 8 + k] - m);
        si[c] = 1.0f / s; gin[c] = am;
    }
    {
        float m = T[c * 8]; int am = 0;
        for (int k = 1; k < 8; ++k) { float v = T[c * 8 + k]; if (v > m) { m = v; am = k; } }
        float s = 0.f;
        for (int k = 0; k < 8; ++k) s += expf(T[c * 8 + k] - m);
        so[c] = 1.0f / s; gout[c] = am;
    }
    __syncthreads();
    const int g = gin[c], go = gout[c];
    int r1 = 0, r2 = 0;  // stable rank within group
    for (int i = 0; i < c; ++i) { r1 += (gin[i] == g); r2 += (gout[i] == go); }
    if (c < 8) {
        int n1 = 0, n2 = 0;
        for (int i = 0; i < 256; ++i) { n1 += (gin[i] == c); n2 += (gout[i] == c); }
        cnt_in[c] = n1; cnt_out[c] = n2;
    }
    __syncthreads();
    if (c == 0) {
        int a = 0, b = 0;
        for (int k = 0; k < 8; ++k) { cb[k] = a; a += cnt_in[k]; fb[k] = b; b += cnt_out[k]; }
    }
    __syncthreads();
    meta[M_CLIST + cb[g] + r1] = c;
    perm[fb[go] + r2] = c;               // = argsort(t stable)
    __syncthreads();
    const int ppc = perm[perm[c]];       // pp[j], j = c
    destl[ppc] = c;                      // dest[pp[j]] = j
    __syncthreads();
    ((float*)meta)[M_SI + c] = si[c];
    ((float*)meta)[M_SO + c] = so[c];
    meta[M_FLIST + c] = perm[c];
    meta[M_DEST + c]  = destl[c];
    if (c < 8) {
        meta[M_CBASE + c] = cb[c];
        meta[M_FBASE + c] = fb[c];
        meta[M_CCNT + c]  = cnt_in[c];
        meta[M_FCNT + c]  = cnt_out[c];
    }
    if (c == 0) {
        int a = 0;
        for (int k = 0; k < 8; ++k) {
            meta[M_WOFFE + k] = a;
            const int nq  = (cnt_in[k] + 31) >> 5;
            const int mfa = (cnt_out[k] + 15) >> 4;
            a += nq * mfa * 9 * 512;
        }
        meta[M_WOFFE + 8] = a;
    }
}

// wpack: per group, [q][mf][tap][lane 0..63][j 0..7] bf16 in exact A-fragment
// lane order for mfma_f32_16x16x32_bf16: f = mf*16 + (lane&15), c = q*32 + (lane>>4)*8 + j.
__global__ void flgc_pack(const float* __restrict__ conv, const int* __restrict__ meta,
                          unsigned short* __restrict__ wpack) {
    const float* si = (const float*)meta + M_SI;
    const float* so = (const float*)meta + M_SO;
    const int total = meta[M_WOFFE + 8];
    for (int idx = blockIdx.x * blockDim.x + threadIdx.x; idx < total;
         idx += gridDim.x * blockDim.x) {
        int gg = 0;
        while (gg < 7 && idx >= meta[M_WOFFE + gg + 1]) ++gg;
        const int local = idx - meta[M_WOFFE + gg];
        const int fcnt = meta[M_FCNT + gg], ccnt = meta[M_CCNT + gg];
        const int mfall = (fcnt + 15) >> 4;
        const int fragidx = local >> 9, e = local & 511;
        const int lane = e >> 3, j = e & 7;
        const int tap = fragidx % 9, t2 = fragidx / 9;
        const int mf = t2 % mfall, q = t2 / mfall;
        const int fl = mf * 16 + (lane & 15);
        const int cl = q * 32 + (lane >> 4) * 8 + j;
        float v = 0.f;
        if (fl < fcnt && cl < ccnt) {
            const int F  = meta[M_FLIST + meta[M_FBASE + gg] + fl];
            const int CH = meta[M_CLIST + meta[M_CBASE + gg] + cl];
            v = conv[(F * 256 + CH) * 9 + tap] * si[CH] * so[F];
        }
        wpack[idx] = f2bf(v);
    }
}

// ---- reorder x -> xr[g*2+q][b][row 0..57][col 0..57][chunk-swizzled cl] bf16.
// Chunk position within each 64B col-group is XOR-swizzled: chunk' = chunk ^ ((col>>1)&3)
// so that conv's B-frag ds_read_b128 is ~conflict-free (read applies the same XOR).
__global__ __launch_bounds__(256) void flgc_reorder(const float* __restrict__ x,
                                                    const int* __restrict__ meta,
                                                    unsigned short* __restrict__ xr) {
    __shared__ float lds[32][65];
    const int r = blockIdx.x;           // xr row 0..57
    const int b = blockIdx.y;
    const int slot = blockIdx.z;        // g*2+q
    const int g = slot >> 1, q = slot & 1;
    const int ccnt = meta[M_CCNT + g];
    int nq = (ccnt + 31) >> 5; if (nq > 2) nq = 2;
    if (q >= nq) return;
    const int cbas = meta[M_CBASE + g];
    const int row = r - 1;
    const int colx = threadIdx.x & 63;
    const int cl0 = threadIdx.x >> 6;   // 0..3 (wave id)
    const int ic = colx - 1;
    const bool ok = ((unsigned)row < 56u) && ((unsigned)ic < 56u);

    int chn[8];
#pragma unroll
    for (int i = 0; i < 8; ++i) {
        const int cgl = q * 32 + cl0 + i * 4;
        chn[i] = (cgl < ccnt) ? meta[M_CLIST + cbas + cgl] : -1;
    }
    const float* xb = x + (size_t)b * 256 * 3136 + row * 56 + ic;
    float v[8];
#pragma unroll
    for (int i = 0; i < 8; ++i) v[i] = 0.f;
#pragma unroll
    for (int i = 0; i < 8; ++i)          // 8 independent loads, all in flight
        if (ok && chn[i] >= 0) v[i] = xb[(size_t)chn[i] * 3136];
#pragma unroll
    for (int i = 0; i < 8; ++i) lds[cl0 + i * 4][colx] = v[i];
    __syncthreads();

    unsigned short* dst = xr + (size_t)(slot * 32 + b) * 107648ull + r * 58 * 32;
    for (int i = threadIdx.x; i < 58 * 8; i += 256) {
        const int col = i >> 3, c8 = i & 7;
        const int chunk = c8 >> 1, lo = (c8 & 1) * 4;
        const int cl4 = chunk * 8 + lo;            // source channels cl4..cl4+3
        ushort4 pk = make_ushort4(f2bf(lds[cl4 + 0][col]), f2bf(lds[cl4 + 1][col]),
                                  f2bf(lds[cl4 + 2][col]), f2bf(lds[cl4 + 3][col]));
        const int schunk = chunk ^ ((col >> 1) & 3);
        *(ushort4*)&dst[col * 32 + schunk * 8 + lo] = pk;
    }
}

// ---- pipelined conv: block=(b,g) persistent over 7 stripes x nq q-phases.
// Double-buffered x staging with counted vmcnt(10); weights staged once (mfe<=4).
// LDS: xbuf 2x40KB + wbuf 72KB = 152 KB -> 1 block/CU.
__global__ __launch_bounds__(256, 1) void flgc_conv_p(const int* __restrict__ meta,
                                                      const unsigned short* __restrict__ wpack,
                                                      const unsigned short* __restrict__ xr,
                                                      float* __restrict__ out) {
    __shared__ __align__(16) unsigned short xbuf[2][CHX * 512];   // 2 x 40960 B
    __shared__ __align__(16) unsigned short wbuf[2 * 4 * 9 * 512];// 73728 B [q][mf4][tap][512]
    const int b = blockIdx.x, g = blockIdx.y;
    const int tid = threadIdx.x, lane = tid & 63, wv = tid >> 6;
    const int ccnt = meta[M_CCNT + g], fcnt = meta[M_FCNT + g];
    const int fbas = meta[M_FBASE + g], woffe = meta[M_WOFFE + g];
    int nq = (ccnt + 31) >> 5; if (nq > 2) nq = 2;
    const int mfall = (fcnt + 15) >> 4;
    if (mfall == 0) return;
    const int n = lane & 15, kg = lane >> 4;
    const int prow = 2 * wv + (n >> 3), pcol = n & 7;
    const size_t slotbase = ((size_t)(g * 2) * 32 + b) * 107648ull;
    const size_t qstride = 32ull * 107648ull;

    for (int mf0 = 0; mf0 < mfall; mf0 += 4) {
        const int mfe = min(4, mfall - mf0);
        // ---- per-thread output-channel map for this mf-chunk ----
        int ocv[4][4];
#pragma unroll
        for (int mf = 0; mf < 4; ++mf)
#pragma unroll
            for (int reg = 0; reg < 4; ++reg) {
                const int fl = (mf0 + mf) * 16 + (lane >> 4) * 4 + reg;
                int oc = -1;
                if (mf < mfe && fl < fcnt)
                    oc = meta[M_DEST + meta[M_FLIST + fbas + fl]];
                ocv[mf][reg] = oc;
            }
        if (nq == 0) {
            // no input channels: masked weights are all zero -> write zeros
            for (int s = 0; s < 7; ++s) {
                const int h = s * 8 + prow;
#pragma unroll
                for (int mf = 0; mf < 4; ++mf)
#pragma unroll
                    for (int reg = 0; reg < 4; ++reg)
                        if (ocv[mf][reg] >= 0) {
                            float* op = out + ((size_t)(b * 256 + ocv[mf][reg]) * 56 + h) * 56 + pcol;
#pragma unroll
                            for (int cg = 0; cg < 7; ++cg) op[cg * 8] = 0.f;
                        }
            }
            continue;
        }
        // ---- stage weights for this chunk (all q, mfe, taps) ----
        __syncthreads();
        const int wch = nq * mfe * 9;
        for (int k = wv; k < wch; k += 4) {
            const int q = k / (mfe * 9), r = k - q * mfe * 9;
            const int mf = r / 9, tap = r - mf * 9;
            const unsigned short* src =
                wpack + woffe + ((size_t)(q * mfall + mf0 + mf) * 9 + tap) * 512 + lane * 8;
            gl_lds16(src, &wbuf[((q * 4 + mf) * 9 + tap) * 512 + lane * 8]);
        }
        __syncthreads();   // vmcnt(0) drain: wbuf ready

        const int P = 7 * nq;
        // prologue: issue phase 0 (s=0, q=0)
        for (int k = wv; k < CHX; k += 4)
            gl_lds16((const char*)(xr + slotbase) + k * 1024 + lane * 16,
                     (char*)&xbuf[0][0] + k * 1024);
        f32x4 acc[4][7];
        for (int p = 0; p < P; ++p) {
            const int s = p / nq, q = p - s * nq;
            if (p + 1 < P) {   // issue next phase's tile into the other buffer
                const int s2 = (p + 1) / nq, q2 = (p + 1) - s2 * nq;
                const size_t base = slotbase + (size_t)q2 * qstride + (size_t)s2 * 14848;
                for (int k = wv; k < CHX; k += 4)
                    gl_lds16((const char*)(xr + base) + k * 1024 + lane * 16,
                             (char*)&xbuf[(p + 1) & 1][0] + k * 1024);
                asm volatile("s_waitcnt vmcnt(10)" ::: "memory");   // own current drained
            } else {
                asm volatile("s_waitcnt vmcnt(0)" ::: "memory");
            }
            __builtin_amdgcn_s_barrier();
            __builtin_amdgcn_sched_barrier(0);
            const unsigned short* xb = &xbuf[p & 1][0];
            if (q == 0) {
#pragma unroll
                for (int mf = 0; mf < 4; ++mf)
#pragma unroll
                    for (int cg = 0; cg < 7; ++cg) acc[mf][cg] = (f32x4){0.f, 0.f, 0.f, 0.f};
            }
#pragma unroll
            for (int tap = 0; tap < 9; ++tap) {
                const int dr = tap / 3, dc = tap - dr * 3;
                bf16x8 A[4];
#pragma unroll
                for (int mf = 0; mf < 4; ++mf)
                    if (mf < mfe)
                        A[mf] = *(const bf16x8*)&wbuf[((q * 4 + mf) * 9 + tap) * 512 + lane * 8];
                const int rb = (prow + dr) * 58;
#pragma unroll
                for (int cg = 0; cg < 7; ++cg) {
                    const int colx = pcol + cg * 8 + dc;
                    const bf16x8 B = *(const bf16x8*)
                        &xb[(rb + colx) * 32 + ((kg ^ ((colx >> 1) & 3)) << 3)];
#pragma unroll
                    for (int mf = 0; mf < 4; ++mf)
                        if (mf < mfe)
                            acc[mf][cg] = __builtin_amdgcn_mfma_f32_16x16x32_bf16(
                                A[mf], B, acc[mf][cg], 0, 0, 0);
                }
            }
            if (q == nq - 1) {   // store stripe s
                const int h = s * 8 + prow;
#pragma unroll
                for (int mf = 0; mf < 4; ++mf)
#pragma unroll
                    for (int reg = 0; reg < 4; ++reg) {
                        const int oc = ocv[mf][reg];
                        if (oc >= 0) {
                            float* op = out + ((size_t)(b * 256 + oc) * 56 + h) * 56 + pcol;
#pragma unroll
                            for (int cg = 0; cg < 7; ++cg) op[cg * 8] = acc[mf][cg][reg];
                        }
                    }
            }
            __builtin_amdgcn_sched_barrier(0);
            __builtin_amdgcn_s_barrier();
        }
    }
}

// ---- fallback (small ws): round-2 direct-gather MFMA kernel, known-good.
__global__ __launch_bounds__(256, 2) void flgc_conv_mfma(const float* __restrict__ x,
                                                         const int* __restrict__ meta,
                                                         const unsigned short* __restrict__ wpack,
                                                         float* __restrict__ out) {
    __shared__ __align__(16) unsigned short xlds[10 * 4 * 64 * 8];
    __shared__ __align__(16) unsigned short wlds[4 * 9 * 512];
    const int g = blockIdx.z, b = blockIdx.y, h0 = blockIdx.x * 8;
    const int tid = threadIdx.x, lane = tid & 63, wv = tid >> 6;
    const int ccnt = meta[M_CCNT + g], fcnt = meta[M_FCNT + g];
    const int cbas = meta[M_CBASE + g], fbas = meta[M_FBASE + g];
    const int woffe = meta[M_WOFFE + g];
    const int nq = (ccnt + 31) >> 5, mfall = (fcnt + 15) >> 4;
    if (mfall == 0) return;
    const int n = lane & 15, kgl = lane >> 4;
    const int prow = 2 * wv + (n >> 3);
    const int pcol = n & 7;

    for (int mf0 = 0; mf0 < mfall; mf0 += 4) {
        const int mfe = min(4, mfall - mf0);
        f32x4 acc[4][7];
#pragma unroll
        for (int mf = 0; mf < 4; ++mf)
#pragma unroll
            for (int cg = 0; cg < 7; ++cg) acc[mf][cg] = (f32x4){0.f, 0.f, 0.f, 0.f};

        for (int q = 0; q < nq; ++q) {
            __syncthreads();
            for (int widx = wv; widx < mfe * 9; widx += 4) {
                const int mf = widx / 9, tap = widx - mf * 9;
                const unsigned short* src =
                    wpack + woffe + (((q * mfall) + mf0 + mf) * 9 + tap) * 512 + lane * 8;
                *(bf16x8*)&wlds[(mf * 9 + tap) * 512 + lane * 8] = *(const bf16x8*)src;
            }
            for (int i = tid; i < 80 * 64; i += 256) {
                const int colx = i & 63, t = i >> 6;
                const int rr = t >> 3, cq = t & 7;
                const int c0 = q * 32 + cq * 4;
                const int row = h0 + rr - 1, ic = colx - 1;
                float v0 = 0.f, v1 = 0.f, v2 = 0.f, v3 = 0.f;
                if ((unsigned)row < 56u && (unsigned)ic < 56u) {
                    const float* xp = x + (size_t)(b * 256) * 3136 + row * 56 + ic;
                    if (c0 + 0 < ccnt) v0 = xp[(size_t)meta[M_CLIST + cbas + c0 + 0] * 3136];
                    if (c0 + 1 < ccnt) v1 = xp[(size_t)meta[M_CLIST + cbas + c0 + 1] * 3136];
                    if (c0 + 2 < ccnt) v2 = xp[(size_t)meta[M_CLIST + cbas + c0 + 2] * 3136];
                    if (c0 + 3 < ccnt) v3 = xp[(size_t)meta[M_CLIST + cbas + c0 + 3] * 3136];
                }
                ushort4 pk = make_ushort4(f2bf(v0), f2bf(v1), f2bf(v2), f2bf(v3));
                *(ushort4*)&xlds[(((rr * 4 + (cq >> 1)) * 64 + colx) << 3) + ((cq & 1) << 2)] = pk;
            }
            __syncthreads();
#pragma unroll
            for (int tap = 0; tap < 9; ++tap) {
                const int dr = tap / 3, dcp = tap - dr * 3;
                bf16x8 A[4];
#pragma unroll
                for (int mf = 0; mf < 4; ++mf)
                    if (mf < mfe)
                        A[mf] = *(bf16x8*)&wlds[(mf * 9 + tap) * 512 + lane * 8];
                const int row_r = prow + dr;
                const int xbase = ((row_r * 4 + kgl) * 64) << 3;
#pragma unroll
                for (int cg = 0; cg < 7; ++cg) {
                    const int cc = cg * 8 + pcol + dcp;
                    const bf16x8 B = *(bf16x8*)&xlds[xbase + (cc << 3)];
#pragma unroll
                    for (int mf = 0; mf < 4; ++mf)
                        if (mf < mfe)
                            acc[mf][cg] = __builtin_amdgcn_mfma_f32_16x16x32_bf16(
                                A[mf], B, acc[mf][cg], 0, 0, 0);
                }
            }
        }
#pragma unroll
        for (int mf = 0; mf < 4; ++mf) {
            if (mf < mfe) {
#pragma unroll
                for (int reg = 0; reg < 4; ++reg) {
                    const int fl = (mf0 + mf) * 16 + (lane >> 4) * 4 + reg;
                    if (fl < fcnt) {
                        const int F  = meta[M_FLIST + fbas + fl];
                        const int oc = meta[M_DEST + F];
                        float* op = out + ((size_t)(b * 256 + oc) * 56 + (h0 + prow)) * 56 + pcol;
#pragma unroll
                        for (int cg = 0; cg < 7; ++cg)
                            op[cg * 8] = acc[mf][cg][reg];
                    }
                }
            }
        }
    }
}

extern "C" void kernel_launch(void* const* d_in, const int* in_sizes, int n_in,
                              void* d_out, int out_size, void* d_ws, size_t ws_size,
                              hipStream_t stream) {
    const float* x    = (const float*)d_in[0];   // [32,256,56,56]
    const float* conv = (const float*)d_in[1];   // [256,256,3,3]
    const float* S    = (const float*)d_in[2];   // [256,8]
    const float* T    = (const float*)d_in[3];   // [256,8]
    float* out = (float*)d_out;                  // [32,256,56,56]
    int* meta = (int*)d_ws;
    unsigned short* wpack = (unsigned short*)((char*)d_ws + WPACK_BYTE_OFF);
    unsigned short* xr    = (unsigned short*)((char*)d_ws + XR_BYTE_OFF);

    flgc_setup<<<1, 256, 0, stream>>>(S, T, meta);
    flgc_pack<<<256, 256, 0, stream>>>(conv, meta, wpack);

    const size_t need = (size_t)XR_BYTE_OFF + 16ull * SLOT_BYTES + 65536;
    if (ws_size >= need) {
        flgc_reorder<<<dim3(58, 32, 16), 256, 0, stream>>>(x, meta, xr);
        flgc_conv_p<<<dim3(32, 8), 256, 0, stream>>>(meta, wpack, xr, out);
    } else {
        flgc_conv_mfma<<<dim3(7, 32, 8), 256, 0, stream>>>(x, meta, wpack, out);
    }
}

// Round 6
// 127.186 us; speedup vs baseline: 1.2354x; 1.2354x over previous
//
#include <hip/hip_runtime.h>

// ---------------- meta layout in d_ws, units of 4 bytes ----------------
#define M_SI    0      // f32[256] softmax max-prob per input channel
#define M_SO    256    // f32[256] per filter
#define M_CLIST 512    // i32[256] input channels, group-major stable
#define M_FLIST 768    // i32[256] filters, group-major stable (= perm)
#define M_DEST  1024   // i32[256] dest[f] = output channel for filter f
#define M_CBASE 1280   // i32[8]
#define M_FBASE 1288   // i32[8]
#define M_CCNT  1296   // i32[8]
#define M_FCNT  1304   // i32[8]
#define M_WOFFE 1312   // i32[9] element offsets into wpack, [8]=total
#define WPACK_BYTE_OFF 16384
#define XR_BYTE_OFF   (4u << 20)          // 4 MB
#define SLOT_ELEMS    3444736ull          // 32 b * 58*58 * 32 ch (bf16 elems)
#define SLOT_BYTES    (SLOT_ELEMS * 2ull)

typedef short bf16x8 __attribute__((ext_vector_type(8)));
typedef float f32x4  __attribute__((ext_vector_type(4)));

__device__ __forceinline__ unsigned short f2bf(float f) {
    unsigned u = __float_as_uint(f);
    u += 0x7fffu + ((u >> 16) & 1u);
    return (unsigned short)(u >> 16);
}

__device__ __forceinline__ void gl_lds16(const void* g, void* l) {
    __builtin_amdgcn_global_load_lds((const __attribute__((address_space(1))) unsigned int*)g,
                                     (__attribute__((address_space(3))) unsigned int*)l, 16, 0, 0);
}

__global__ __launch_bounds__(256) void flgc_setup(const float* __restrict__ S,
                                                  const float* __restrict__ T,
                                                  int* __restrict__ meta) {
    __shared__ float si[256], so[256];
    __shared__ int gin[256], gout[256];
    __shared__ int cnt_in[8], cnt_out[8], cb[8], fb[8];
    __shared__ int perm[256], destl[256];
    const int c = threadIdx.x;  // 0..255

    {   // softmax max-prob + argmax (first occurrence) for S row c
        float m = S[c * 8]; int am = 0;
        for (int k = 1; k < 8; ++k) { float v = S[c * 8 + k]; if (v > m) { m = v; am = k; } }
        float s = 0.f;
        for (int k = 0; k < 8; ++k) s += expf(S[c * 8 + k] - m);
        si[c] = 1.0f / s; gin[c] = am;
    }
    {
        float m = T[c * 8]; int am = 0;
        for (int k = 1; k < 8; ++k) { float v = T[c * 8 + k]; if (v > m) { m = v; am = k; } }
        float s = 0.f;
        for (int k = 0; k < 8; ++k) s += expf(T[c * 8 + k] - m);
        so[c] = 1.0f / s; gout[c] = am;
    }
    __syncthreads();
    const int g = gin[c], go = gout[c];
    int r1 = 0, r2 = 0;  // stable rank within group
    for (int i = 0; i < c; ++i) { r1 += (gin[i] == g); r2 += (gout[i] == go); }
    if (c < 8) {
        int n1 = 0, n2 = 0;
        for (int i = 0; i < 256; ++i) { n1 += (gin[i] == c); n2 += (gout[i] == c); }
        cnt_in[c] = n1; cnt_out[c] = n2;
    }
    __syncthreads();
    if (c == 0) {
        int a = 0, b = 0;
        for (int k = 0; k < 8; ++k) { cb[k] = a; a += cnt_in[k]; fb[k] = b; b += cnt_out[k]; }
    }
    __syncthreads();
    meta[M_CLIST + cb[g] + r1] = c;
    perm[fb[go] + r2] = c;               // = argsort(t stable)
    __syncthreads();
    const int ppc = perm[perm[c]];       // pp[j], j = c
    destl[ppc] = c;                      // dest[pp[j]] = j
    __syncthreads();
    ((float*)meta)[M_SI + c] = si[c];
    ((float*)meta)[M_SO + c] = so[c];
    meta[M_FLIST + c] = perm[c];
    meta[M_DEST + c]  = destl[c];
    if (c < 8) {
        meta[M_CBASE + c] = cb[c];
        meta[M_FBASE + c] = fb[c];
        meta[M_CCNT + c]  = cnt_in[c];
        meta[M_FCNT + c]  = cnt_out[c];
    }
    if (c == 0) {
        int a = 0;
        for (int k = 0; k < 8; ++k) {
            meta[M_WOFFE + k] = a;
            const int nq  = (cnt_in[k] + 31) >> 5;
            const int mfa = (cnt_out[k] + 15) >> 4;
            a += nq * mfa * 9 * 512;
        }
        meta[M_WOFFE + 8] = a;
    }
}

// wpack: per group, [q][mf][tap][lane 0..63][j 0..7] bf16 in exact A-fragment
// lane order for mfma_f32_16x16x32_bf16: f = mf*16 + (lane&15), c = q*32 + (lane>>4)*8 + j.
__global__ void flgc_pack(const float* __restrict__ conv, const int* __restrict__ meta,
                          unsigned short* __restrict__ wpack) {
    const float* si = (const float*)meta + M_SI;
    const float* so = (const float*)meta + M_SO;
    const int total = meta[M_WOFFE + 8];
    for (int idx = blockIdx.x * blockDim.x + threadIdx.x; idx < total;
         idx += gridDim.x * blockDim.x) {
        int gg = 0;
        while (gg < 7 && idx >= meta[M_WOFFE + gg + 1]) ++gg;
        const int local = idx - meta[M_WOFFE + gg];
        const int fcnt = meta[M_FCNT + gg], ccnt = meta[M_CCNT + gg];
        const int mfall = (fcnt + 15) >> 4;
        const int fragidx = local >> 9, e = local & 511;
        const int lane = e >> 3, j = e & 7;
        const int tap = fragidx % 9, t2 = fragidx / 9;
        const int mf = t2 % mfall, q = t2 / mfall;
        const int fl = mf * 16 + (lane & 15);
        const int cl = q * 32 + (lane >> 4) * 8 + j;
        float v = 0.f;
        if (fl < fcnt && cl < ccnt) {
            const int F  = meta[M_FLIST + meta[M_FBASE + gg] + fl];
            const int CH = meta[M_CLIST + meta[M_CBASE + gg] + cl];
            v = conv[(F * 256 + CH) * 9 + tap] * si[CH] * so[F];
        }
        wpack[idx] = f2bf(v);
    }
}

// ---- reorder x -> xr[g*2+q][b][row 0..57][col 0..57][chunk-swizzled cl] bf16.
// Chunk position within each 64B col-group is XOR-swizzled: chunk' = chunk ^ ((col>>1)&3).
__global__ __launch_bounds__(256) void flgc_reorder(const float* __restrict__ x,
                                                    const int* __restrict__ meta,
                                                    unsigned short* __restrict__ xr) {
    __shared__ float lds[32][65];
    const int r = blockIdx.x;           // xr row 0..57
    const int b = blockIdx.y;
    const int slot = blockIdx.z;        // g*2+q
    const int g = slot >> 1, q = slot & 1;
    const int ccnt = meta[M_CCNT + g];
    int nq = (ccnt + 31) >> 5; if (nq > 2) nq = 2;
    if (q >= nq) return;
    const int cbas = meta[M_CBASE + g];
    const int row = r - 1;
    const int colx = threadIdx.x & 63;
    const int cl0 = threadIdx.x >> 6;   // 0..3 (wave id)
    const int ic = colx - 1;
    const bool ok = ((unsigned)row < 56u) && ((unsigned)ic < 56u);

    int chn[8];
#pragma unroll
    for (int i = 0; i < 8; ++i) {
        const int cgl = q * 32 + cl0 + i * 4;
        chn[i] = (cgl < ccnt) ? meta[M_CLIST + cbas + cgl] : -1;
    }
    const float* xb = x + (size_t)b * 256 * 3136 + row * 56 + ic;
    float v[8];
#pragma unroll
    for (int i = 0; i < 8; ++i) v[i] = 0.f;
#pragma unroll
    for (int i = 0; i < 8; ++i)          // 8 independent loads, all in flight
        if (ok && chn[i] >= 0) v[i] = xb[(size_t)chn[i] * 3136];
#pragma unroll
    for (int i = 0; i < 8; ++i) lds[cl0 + i * 4][colx] = v[i];
    __syncthreads();

    unsigned short* dst = xr + (size_t)(slot * 32 + b) * 107648ull + r * 58 * 32;
    for (int i = threadIdx.x; i < 58 * 8; i += 256) {
        const int col = i >> 3, c8 = i & 7;
        const int chunk = c8 >> 1, lo = (c8 & 1) * 4;
        const int cl4 = chunk * 8 + lo;            // source channels cl4..cl4+3
        ushort4 pk = make_ushort4(f2bf(lds[cl4 + 0][col]), f2bf(lds[cl4 + 1][col]),
                                  f2bf(lds[cl4 + 2][col]), f2bf(lds[cl4 + 3][col]));
        const int schunk = chunk ^ ((col >> 1) & 3);
        *(ushort4*)&dst[col * 32 + schunk * 8 + lo] = pk;
    }
}

// ============ register-A pipelined conv ============
// Block=(b,g,z), 4 waves, 4-row stripes s = z+4k (14 stripes over z=0..3).
// A-fragments live in VGPRs (L2-hot wpack); LDS holds only the double-buffered
// x tile (2 x 6rows x 58cols x 32ch bf16 = 44.5 KB) -> 2 blocks/CU.
// Per phase: issue next tile (6 gl_lds16/wave) -> vmcnt(6) -> barrier -> MFMA.

#define TAPS(Q)                                                                              \
    _Pragma("unroll") for (int tap = 0; tap < 9; ++tap) {                                    \
        const int dr = tap / 3, dc = tap - dr * 3;                                           \
        const int rowb = ((wv + dr) * 58) << 6;                                              \
        _Pragma("unroll") for (int cg = 0; cg < 4; ++cg) {                                   \
            const bf16x8 Bv = *(const bf16x8*)((const char*)xb + rowb + addrc[cg][dc]);      \
            _Pragma("unroll") for (int mf = 0; mf < MFE; ++mf)                               \
                acc[mf][cg] = __builtin_amdgcn_mfma_f32_16x16x32_bf16(                       \
                    A[Q][mf][tap], Bv, acc[mf][cg], 0, 0, 0);                                \
        }                                                                                    \
    }

template <int NQ, int MFE>
__device__ __forceinline__ void conv_pass(
    const unsigned short* __restrict__ wpack, const unsigned short* __restrict__ xr,
    float* __restrict__ out, unsigned short* xbufA, unsigned short* xbufB,
    const int (&ocv)[2][4], int b, int g, int z, int mf0, int mfall, int woffe,
    int lane, int wv) {
    const int nn = lane & 15, kg = lane >> 4;
    // ---- A fragments in registers (static indexing only) ----
    bf16x8 A[NQ][MFE][9];
#pragma unroll
    for (int q = 0; q < NQ; ++q)
#pragma unroll
        for (int mf = 0; mf < MFE; ++mf)
#pragma unroll
            for (int tap = 0; tap < 9; ++tap)
                A[q][mf][tap] = *(const bf16x8*)
                    &wpack[woffe + ((size_t)((q * mfall) + (mf0 + mf)) * 9 + tap) * 512 + lane * 8];
    // ---- precomputed B column byte-offsets (phase-invariant) ----
    int addrc[4][3];
#pragma unroll
    for (int cg = 0; cg < 4; ++cg)
#pragma unroll
        for (int dc = 0; dc < 3; ++dc) {
            int ccol = cg * 16 + nn + dc; if (ccol > 57) ccol = 57;
            addrc[cg][dc] = (ccol << 6) + ((kg ^ ((ccol >> 1) & 3)) << 4);
        }
    const int ns = (z < 2) ? 4 : 3;
    const int P = ns * NQ;
    const int base = wv * 348;
    // ---- prologue: stage tile for phase 0 (s=z, q=0) into xbufA ----
    {
        const char* src = (const char*)(xr + (size_t)((g * 2) * 32 + b) * 107648ull
                                        + (size_t)(4 * z) * 1856);
        char* dstb = (char*)xbufA;
#pragma unroll
        for (int j = 0; j < 5; ++j)
            gl_lds16(src + (size_t)(base + j * 64 + lane) * 16, dstb + (base + j * 64) * 16);
        if (lane < 28)
            gl_lds16(src + (size_t)(base + 320 + lane) * 16, dstb + (base + 320) * 16);
    }
    f32x4 acc[MFE][4];
    for (int p = 0; p < P; ++p) {
        if (p + 1 < P) {
            const int pn = p + 1;
            const int sp = z + 4 * (pn / NQ);
            const int qp = (NQ == 2) ? (pn & 1) : 0;
            const char* src = (const char*)(xr + (size_t)((g * 2 + qp) * 32 + b) * 107648ull
                                            + (size_t)(4 * sp) * 1856);
            char* dstb = (char*)((pn & 1) ? xbufB : xbufA);
#pragma unroll
            for (int j = 0; j < 5; ++j)
                gl_lds16(src + (size_t)(base + j * 64 + lane) * 16, dstb + (base + j * 64) * 16);
            if (lane < 28)
                gl_lds16(src + (size_t)(base + 320 + lane) * 16, dstb + (base + 320) * 16);
            asm volatile("s_waitcnt vmcnt(6)" ::: "memory");   // current tile drained
        } else {
            asm volatile("s_waitcnt vmcnt(0)" ::: "memory");
        }
        __builtin_amdgcn_s_barrier();
        __builtin_amdgcn_sched_barrier(0);
        const unsigned short* xb = (p & 1) ? xbufB : xbufA;
        const int s = z + 4 * ((NQ == 2) ? (p >> 1) : p);
        if (NQ == 1 || (p & 1) == 0) {
#pragma unroll
            for (int mf = 0; mf < MFE; ++mf)
#pragma unroll
                for (int cg = 0; cg < 4; ++cg) acc[mf][cg] = (f32x4){0.f, 0.f, 0.f, 0.f};
        }
        if (NQ == 2 && (p & 1)) { TAPS(1) } else { TAPS(0) }
        if (NQ == 1 || (p & 1)) {       // last q-phase of this stripe: store
            const int h = 4 * s + wv;
#pragma unroll
            for (int mf = 0; mf < MFE; ++mf)
#pragma unroll
                for (int reg = 0; reg < 4; ++reg) {
                    const int oc = ocv[mf][reg];
                    if (oc >= 0) {
                        float* op = out + ((size_t)(b * 256 + oc) * 56 + h) * 56;
#pragma unroll
                        for (int cg = 0; cg < 4; ++cg) {
                            const int col = cg * 16 + nn;
                            if (col < 56) op[col] = acc[mf][cg][reg];
                        }
                    }
                }
        }
        __builtin_amdgcn_sched_barrier(0);
        __builtin_amdgcn_s_barrier();
    }
}

__global__ __launch_bounds__(256, 2) void flgc_conv_r(const int* __restrict__ meta,
                                                      const unsigned short* __restrict__ wpack,
                                                      const unsigned short* __restrict__ xr,
                                                      float* __restrict__ out) {
    __shared__ __align__(16) unsigned short xbufA[11136];   // 22272 B
    __shared__ __align__(16) unsigned short xbufB[11136];   // 22272 B
    const int b = blockIdx.x, g = blockIdx.y, z = blockIdx.z;
    const int tid = threadIdx.x, lane = tid & 63, wv = tid >> 6;
    const int ccnt = meta[M_CCNT + g], fcnt = meta[M_FCNT + g];
    const int fbas = meta[M_FBASE + g], woffe = meta[M_WOFFE + g];
    int nq = (ccnt + 31) >> 5; if (nq > 2) nq = 2;
    const int mfall = (fcnt + 15) >> 4;
    if (mfall == 0) return;
    const int nn = lane & 15;

    for (int mf0 = 0; mf0 < mfall; mf0 += 2) {
        const int mfe = min(2, mfall - mf0);
        int ocv[2][4];
#pragma unroll
        for (int mf = 0; mf < 2; ++mf)
#pragma unroll
            for (int reg = 0; reg < 4; ++reg) {
                const int fl = (mf0 + mf) * 16 + (lane >> 4) * 4 + reg;
                ocv[mf][reg] = (mf < mfe && fl < fcnt)
                    ? meta[M_DEST + meta[M_FLIST + fbas + fl]] : -1;
            }
        if (nq == 0) {   // no input channels: outputs are zero
            const int ns = (z < 2) ? 4 : 3;
            for (int si = 0; si < ns; ++si) {
                const int h = 4 * (z + 4 * si) + wv;
#pragma unroll
                for (int mf = 0; mf < 2; ++mf)
#pragma unroll
                    for (int reg = 0; reg < 4; ++reg)
                        if (ocv[mf][reg] >= 0) {
                            float* op = out + ((size_t)(b * 256 + ocv[mf][reg]) * 56 + h) * 56;
#pragma unroll
                            for (int cg = 0; cg < 4; ++cg) {
                                const int col = cg * 16 + nn;
                                if (col < 56) op[col] = 0.f;
                            }
                        }
            }
            continue;
        }
        if (nq == 1) {
            if (mfe == 2) conv_pass<1, 2>(wpack, xr, out, xbufA, xbufB, ocv, b, g, z, mf0, mfall, woffe, lane, wv);
            else          conv_pass<1, 1>(wpack, xr, out, xbufA, xbufB, ocv, b, g, z, mf0, mfall, woffe, lane, wv);
        } else {
            if (mfe == 2) conv_pass<2, 2>(wpack, xr, out, xbufA, xbufB, ocv, b, g, z, mf0, mfall, woffe, lane, wv);
            else          conv_pass<2, 1>(wpack, xr, out, xbufA, xbufB, ocv, b, g, z, mf0, mfall, woffe, lane, wv);
        }
    }
}

// ---- fallback (small ws): round-2 direct-gather MFMA kernel, known-good.
__global__ __launch_bounds__(256, 2) void flgc_conv_mfma(const float* __restrict__ x,
                                                         const int* __restrict__ meta,
                                                         const unsigned short* __restrict__ wpack,
                                                         float* __restrict__ out) {
    __shared__ __align__(16) unsigned short xlds[10 * 4 * 64 * 8];
    __shared__ __align__(16) unsigned short wlds[4 * 9 * 512];
    const int g = blockIdx.z, b = blockIdx.y, h0 = blockIdx.x * 8;
    const int tid = threadIdx.x, lane = tid & 63, wv = tid >> 6;
    const int ccnt = meta[M_CCNT + g], fcnt = meta[M_FCNT + g];
    const int cbas = meta[M_CBASE + g], fbas = meta[M_FBASE + g];
    const int woffe = meta[M_WOFFE + g];
    const int nq = (ccnt + 31) >> 5, mfall = (fcnt + 15) >> 4;
    if (mfall == 0) return;
    const int n = lane & 15, kgl = lane >> 4;
    const int prow = 2 * wv + (n >> 3);
    const int pcol = n & 7;

    for (int mf0 = 0; mf0 < mfall; mf0 += 4) {
        const int mfe = min(4, mfall - mf0);
        f32x4 acc[4][7];
#pragma unroll
        for (int mf = 0; mf < 4; ++mf)
#pragma unroll
            for (int cg = 0; cg < 7; ++cg) acc[mf][cg] = (f32x4){0.f, 0.f, 0.f, 0.f};

        for (int q = 0; q < nq; ++q) {
            __syncthreads();
            for (int widx = wv; widx < mfe * 9; widx += 4) {
                const int mf = widx / 9, tap = widx - mf * 9;
                const unsigned short* src =
                    wpack + woffe + (((q * mfall) + mf0 + mf) * 9 + tap) * 512 + lane * 8;
                *(bf16x8*)&wlds[(mf * 9 + tap) * 512 + lane * 8] = *(const bf16x8*)src;
            }
            for (int i = tid; i < 80 * 64; i += 256) {
                const int colx = i & 63, t = i >> 6;
                const int rr = t >> 3, cq = t & 7;
                const int c0 = q * 32 + cq * 4;
                const int row = h0 + rr - 1, ic = colx - 1;
                float v0 = 0.f, v1 = 0.f, v2 = 0.f, v3 = 0.f;
                if ((unsigned)row < 56u && (unsigned)ic < 56u) {
                    const float* xp = x + (size_t)(b * 256) * 3136 + row * 56 + ic;
                    if (c0 + 0 < ccnt) v0 = xp[(size_t)meta[M_CLIST + cbas + c0 + 0] * 3136];
                    if (c0 + 1 < ccnt) v1 = xp[(size_t)meta[M_CLIST + cbas + c0 + 1] * 3136];
                    if (c0 + 2 < ccnt) v2 = xp[(size_t)meta[M_CLIST + cbas + c0 + 2] * 3136];
                    if (c0 + 3 < ccnt) v3 = xp[(size_t)meta[M_CLIST + cbas + c0 + 3] * 3136];
                }
                ushort4 pk = make_ushort4(f2bf(v0), f2bf(v1), f2bf(v2), f2bf(v3));
                *(ushort4*)&xlds[(((rr * 4 + (cq >> 1)) * 64 + colx) << 3) + ((cq & 1) << 2)] = pk;
            }
            __syncthreads();
#pragma unroll
            for (int tap = 0; tap < 9; ++tap) {
                const int dr = tap / 3, dcp = tap - dr * 3;
                bf16x8 A[4];
#pragma unroll
                for (int mf = 0; mf < 4; ++mf)
                    if (mf < mfe)
                        A[mf] = *(bf16x8*)&wlds[(mf * 9 + tap) * 512 + lane * 8];
                const int row_r = prow + dr;
                const int xbase = ((row_r * 4 + kgl) * 64) << 3;
#pragma unroll
                for (int cg = 0; cg < 7; ++cg) {
                    const int cc = cg * 8 + pcol + dcp;
                    const bf16x8 B = *(bf16x8*)&xlds[xbase + (cc << 3)];
#pragma unroll
                    for (int mf = 0; mf < 4; ++mf)
                        if (mf < mfe)
                            acc[mf][cg] = __builtin_amdgcn_mfma_f32_16x16x32_bf16(
                                A[mf], B, acc[mf][cg], 0, 0, 0);
                }
            }
        }
#pragma unroll
        for (int mf = 0; mf < 4; ++mf) {
            if (mf < mfe) {
#pragma unroll
                for (int reg = 0; reg < 4; ++reg) {
                    const int fl = (mf0 + mf) * 16 + (lane >> 4) * 4 + reg;
                    if (fl < fcnt) {
                        const int F  = meta[M_FLIST + fbas + fl];
                        const int oc = meta[M_DEST + F];
                        float* op = out + ((size_t)(b * 256 + oc) * 56 + (h0 + prow)) * 56 + pcol;
#pragma unroll
                        for (int cg = 0; cg < 7; ++cg)
                            op[cg * 8] = acc[mf][cg][reg];
                    }
                }
            }
        }
    }
}

extern "C" void kernel_launch(void* const* d_in, const int* in_sizes, int n_in,
                              void* d_out, int out_size, void* d_ws, size_t ws_size,
                              hipStream_t stream) {
    const float* x    = (const float*)d_in[0];   // [32,256,56,56]
    const float* conv = (const float*)d_in[1];   // [256,256,3,3]
    const float* S    = (const float*)d_in[2];   // [256,8]
    const float* T    = (const float*)d_in[3];   // [256,8]
    float* out = (float*)d_out;                  // [32,256,56,56]
    int* meta = (int*)d_ws;
    unsigned short* wpack = (unsigned short*)((char*)d_ws + WPACK_BYTE_OFF);
    unsigned short* xr    = (unsigned short*)((char*)d_ws + XR_BYTE_OFF);

    flgc_setup<<<1, 256, 0, stream>>>(S, T, meta);
    flgc_pack<<<256, 256, 0, stream>>>(conv, meta, wpack);

    const size_t need = (size_t)XR_BYTE_OFF + 16ull * SLOT_BYTES + 65536;
    if (ws_size >= need) {
        flgc_reorder<<<dim3(58, 32, 16), 256, 0, stream>>>(x, meta, xr);
        flgc_conv_r<<<dim3(32, 8, 4), 256, 0, stream>>>(meta, wpack, xr, out);
    } else {
        flgc_conv_mfma<<<dim3(7, 32, 8), 256, 0, stream>>>(x, meta, wpack, out);
    }
}

// Round 7
// 107.006 us; speedup vs baseline: 1.4683x; 1.1886x over previous
//
#include <hip/hip_runtime.h>

// ---------------- meta layout in d_ws, units of 4 bytes ----------------
#define M_SI    0      // f32[256] softmax max-prob per input channel
#define M_SO    256    // f32[256] per filter
#define M_CLIST 512    // i32[256] input channels, group-major stable
#define M_FLIST 768    // i32[256] filters, group-major stable (= perm)
#define M_DEST  1024   // i32[256] dest[f] = output channel for filter f
#define M_CBASE 1280   // i32[8]
#define M_FBASE 1288   // i32[8]
#define M_CCNT  1296   // i32[8]
#define M_FCNT  1304   // i32[8]
#define M_WOFFE 1312   // i32[9] element offsets into wpack, [8]=total
#define WPACK_BYTE_OFF 16384
#define XR_BYTE_OFF   (4u << 20)          // 4 MB
#define SLOT_ELEMS    3444736ull          // 32 b * 58*58 * 32 ch (bf16 elems)
#define SLOT_BYTES    (SLOT_ELEMS * 2ull)

typedef short bf16x8 __attribute__((ext_vector_type(8)));
typedef float f32x4  __attribute__((ext_vector_type(4)));

__device__ __forceinline__ unsigned short f2bf(float f) {
    unsigned u = __float_as_uint(f);
    u += 0x7fffu + ((u >> 16) & 1u);
    return (unsigned short)(u >> 16);
}

__device__ __forceinline__ void gl_lds16(const void* g, void* l) {
    __builtin_amdgcn_global_load_lds((const __attribute__((address_space(1))) unsigned int*)g,
                                     (__attribute__((address_space(3))) unsigned int*)l, 16, 0, 0);
}

__global__ __launch_bounds__(256) void flgc_setup(const float* __restrict__ S,
                                                  const float* __restrict__ T,
                                                  int* __restrict__ meta) {
    __shared__ float si[256], so[256];
    __shared__ int gin[256], gout[256];
    __shared__ int cnt_in[8], cnt_out[8], cb[8], fb[8];
    __shared__ int perm[256], destl[256];
    const int c = threadIdx.x;  // 0..255

    {   // softmax max-prob + argmax (first occurrence) for S row c
        float m = S[c * 8]; int am = 0;
        for (int k = 1; k < 8; ++k) { float v = S[c * 8 + k]; if (v > m) { m = v; am = k; } }
        float s = 0.f;
        for (int k = 0; k < 8; ++k) s += expf(S[c * 8 + k] - m);
        si[c] = 1.0f / s; gin[c] = am;
    }
    {
        float m = T[c * 8]; int am = 0;
        for (int k = 1; k < 8; ++k) { float v = T[c * 8 + k]; if (v > m) { m = v; am = k; } }
        float s = 0.f;
        for (int k = 0; k < 8; ++k) s += expf(T[c * 8 + k] - m);
        so[c] = 1.0f / s; gout[c] = am;
    }
    __syncthreads();
    const int g = gin[c], go = gout[c];
    int r1 = 0, r2 = 0;  // stable rank within group
    for (int i = 0; i < c; ++i) { r1 += (gin[i] == g); r2 += (gout[i] == go); }
    if (c < 8) {
        int n1 = 0, n2 = 0;
        for (int i = 0; i < 256; ++i) { n1 += (gin[i] == c); n2 += (gout[i] == c); }
        cnt_in[c] = n1; cnt_out[c] = n2;
    }
    __syncthreads();
    if (c == 0) {
        int a = 0, b = 0;
        for (int k = 0; k < 8; ++k) { cb[k] = a; a += cnt_in[k]; fb[k] = b; b += cnt_out[k]; }
    }
    __syncthreads();
    meta[M_CLIST + cb[g] + r1] = c;
    perm[fb[go] + r2] = c;               // = argsort(t stable)
    __syncthreads();
    const int ppc = perm[perm[c]];       // pp[j], j = c
    destl[ppc] = c;                      // dest[pp[j]] = j
    __syncthreads();
    ((float*)meta)[M_SI + c] = si[c];
    ((float*)meta)[M_SO + c] = so[c];
    meta[M_FLIST + c] = perm[c];
    meta[M_DEST + c]  = destl[c];
    if (c < 8) {
        meta[M_CBASE + c] = cb[c];
        meta[M_FBASE + c] = fb[c];
        meta[M_CCNT + c]  = cnt_in[c];
        meta[M_FCNT + c]  = cnt_out[c];
    }
    if (c == 0) {
        int a = 0;
        for (int k = 0; k < 8; ++k) {
            meta[M_WOFFE + k] = a;
            const int nq  = (cnt_in[k] + 31) >> 5;
            const int mfa = (cnt_out[k] + 15) >> 4;
            a += nq * mfa * 9 * 512;
        }
        meta[M_WOFFE + 8] = a;
    }
}

// wpack: per group, [q][mf][tap][lane 0..63][j 0..7] bf16 in exact A-fragment
// lane order for mfma_f32_16x16x32_bf16: f = mf*16 + (lane&15), c = q*32 + (lane>>4)*8 + j.
__global__ void flgc_pack(const float* __restrict__ conv, const int* __restrict__ meta,
                          unsigned short* __restrict__ wpack) {
    const float* si = (const float*)meta + M_SI;
    const float* so = (const float*)meta + M_SO;
    const int total = meta[M_WOFFE + 8];
    for (int idx = blockIdx.x * blockDim.x + threadIdx.x; idx < total;
         idx += gridDim.x * blockDim.x) {
        int gg = 0;
        while (gg < 7 && idx >= meta[M_WOFFE + gg + 1]) ++gg;
        const int local = idx - meta[M_WOFFE + gg];
        const int fcnt = meta[M_FCNT + gg], ccnt = meta[M_CCNT + gg];
        const int mfall = (fcnt + 15) >> 4;
        const int fragidx = local >> 9, e = local & 511;
        const int lane = e >> 3, j = e & 7;
        const int tap = fragidx % 9, t2 = fragidx / 9;
        const int mf = t2 % mfall, q = t2 / mfall;
        const int fl = mf * 16 + (lane & 15);
        const int cl = q * 32 + (lane >> 4) * 8 + j;
        float v = 0.f;
        if (fl < fcnt && cl < ccnt) {
            const int F  = meta[M_FLIST + meta[M_FBASE + gg] + fl];
            const int CH = meta[M_CLIST + meta[M_CBASE + gg] + cl];
            v = conv[(F * 256 + CH) * 9 + tap] * si[CH] * so[F];
        }
        wpack[idx] = f2bf(v);
    }
}

// ---- reorder x -> xr[g*2+q][b][row 0..57][col 0..57][chunk-swizzled cl] bf16.
// Chunk position within each 64B col-group is XOR-swizzled: chunk' = chunk ^ ((col>>1)&3).
__global__ __launch_bounds__(256) void flgc_reorder(const float* __restrict__ x,
                                                    const int* __restrict__ meta,
                                                    unsigned short* __restrict__ xr) {
    __shared__ float lds[32][65];
    const int r = blockIdx.x;           // xr row 0..57
    const int b = blockIdx.y;
    const int slot = blockIdx.z;        // g*2+q
    const int g = slot >> 1, q = slot & 1;
    const int ccnt = meta[M_CCNT + g];
    int nq = (ccnt + 31) >> 5; if (nq > 2) nq = 2;
    if (q >= nq) return;
    const int cbas = meta[M_CBASE + g];
    const int row = r - 1;
    const int colx = threadIdx.x & 63;
    const int cl0 = threadIdx.x >> 6;   // 0..3 (wave id)
    const int ic = colx - 1;
    const bool ok = ((unsigned)row < 56u) && ((unsigned)ic < 56u);

    int chn[8];
#pragma unroll
    for (int i = 0; i < 8; ++i) {
        const int cgl = q * 32 + cl0 + i * 4;
        chn[i] = (cgl < ccnt) ? meta[M_CLIST + cbas + cgl] : -1;
    }
    const float* xb = x + (size_t)b * 256 * 3136 + row * 56 + ic;
    float v[8];
#pragma unroll
    for (int i = 0; i < 8; ++i) v[i] = 0.f;
#pragma unroll
    for (int i = 0; i < 8; ++i)          // 8 independent loads, all in flight
        if (ok && chn[i] >= 0) v[i] = xb[(size_t)chn[i] * 3136];
#pragma unroll
    for (int i = 0; i < 8; ++i) lds[cl0 + i * 4][colx] = v[i];
    __syncthreads();

    unsigned short* dst = xr + (size_t)(slot * 32 + b) * 107648ull + r * 58 * 32;
    for (int i = threadIdx.x; i < 58 * 8; i += 256) {
        const int col = i >> 3, c8 = i & 7;
        const int chunk = c8 >> 1, lo = (c8 & 1) * 4;
        const int cl4 = chunk * 8 + lo;            // source channels cl4..cl4+3
        ushort4 pk = make_ushort4(f2bf(lds[cl4 + 0][col]), f2bf(lds[cl4 + 1][col]),
                                  f2bf(lds[cl4 + 2][col]), f2bf(lds[cl4 + 3][col]));
        const int schunk = chunk ^ ((col >> 1) & 3);
        *(ushort4*)&dst[col * 32 + schunk * 8 + lo] = pk;
    }
}

// ============ pipelined conv, per-phase A loads ============
// Block=(b,g,z), 4 waves, 4-row stripes s = z+4k. All mf (<=3) per staged tile.
// Per phase: batch-load A frags (global, L2-hot) -> sched fence -> issue next
// x tile (6 gl_lds16/wave) -> vmcnt(6) [prev tile + A drained, next in flight]
// -> barrier -> 36*MFE MFMA -> store (last q) -> barrier.
template <int MFE>
__device__ __forceinline__ void conv_pass(
    const unsigned short* __restrict__ wpack, const unsigned short* __restrict__ xr,
    float* __restrict__ out, unsigned short* xbufA, unsigned short* xbufB,
    const int (&ocv)[3][4], int b, int g, int z, int nq, int mf0, int mfall, int woffe,
    int lane, int wv) {
    const int nn = lane & 15, kg = lane >> 4;
    // ---- precomputed B column byte-offsets (phase-invariant) ----
    int addrc[4][3];
#pragma unroll
    for (int cg = 0; cg < 4; ++cg)
#pragma unroll
        for (int dc = 0; dc < 3; ++dc) {
            int ccol = cg * 16 + nn + dc; if (ccol > 57) ccol = 57;
            addrc[cg][dc] = (ccol << 6) + ((kg ^ ((ccol >> 1) & 3)) << 4);
        }
    const int ns = (z < 2) ? 4 : 3;
    const int P = ns * nq;
    const int base = wv * 348;
    // ---- prologue: stage tile for phase 0 (s=z, q=0) into xbufA ----
    {
        const char* src = (const char*)(xr + (size_t)((g * 2) * 32 + b) * 107648ull
                                        + (size_t)(4 * z) * 1856);
        char* dstb = (char*)xbufA;
#pragma unroll
        for (int j = 0; j < 5; ++j)
            gl_lds16(src + (size_t)(base + j * 64 + lane) * 16, dstb + (base + j * 64) * 16);
        if (lane < 28)
            gl_lds16(src + (size_t)(base + 320 + lane) * 16, dstb + (base + 320) * 16);
    }
    f32x4 acc[MFE][4];
    for (int p = 0; p < P; ++p) {
        const int q = (nq == 2) ? (p & 1) : 0;
        const int s = z + 4 * ((nq == 2) ? (p >> 1) : p);
        // ---- A fragments for THIS phase: batched independent global loads ----
        bf16x8 A[MFE][9];
        {
            const unsigned short* ap =
                wpack + woffe + ((size_t)(q * mfall + mf0) * 9) * 512 + lane * 8;
#pragma unroll
            for (int mf = 0; mf < MFE; ++mf)
#pragma unroll
                for (int tap = 0; tap < 9; ++tap)
                    A[mf][tap] = *(const bf16x8*)(ap + (size_t)(mf * 9 + tap) * 512);
        }
        __builtin_amdgcn_sched_barrier(0);   // keep A issues ahead of staging issues
        if (p + 1 < P) {
            const int pn = p + 1;
            const int qp = (nq == 2) ? (pn & 1) : 0;
            const int sp = z + 4 * ((nq == 2) ? (pn >> 1) : pn);
            const char* src = (const char*)(xr + (size_t)((g * 2 + qp) * 32 + b) * 107648ull
                                            + (size_t)(4 * sp) * 1856);
            char* dstb = (char*)((pn & 1) ? xbufB : xbufA);
#pragma unroll
            for (int j = 0; j < 5; ++j)
                gl_lds16(src + (size_t)(base + j * 64 + lane) * 16, dstb + (base + j * 64) * 16);
            if (lane < 28)
                gl_lds16(src + (size_t)(base + 320 + lane) * 16, dstb + (base + 320) * 16);
            asm volatile("s_waitcnt vmcnt(6)" ::: "memory");   // prev tile + A drained
        } else {
            asm volatile("s_waitcnt vmcnt(0)" ::: "memory");
        }
        __builtin_amdgcn_s_barrier();
        __builtin_amdgcn_sched_barrier(0);
        const unsigned short* xb = (p & 1) ? xbufB : xbufA;
        if (q == 0) {
#pragma unroll
            for (int mf = 0; mf < MFE; ++mf)
#pragma unroll
                for (int cg = 0; cg < 4; ++cg) acc[mf][cg] = (f32x4){0.f, 0.f, 0.f, 0.f};
        }
#pragma unroll
        for (int tap = 0; tap < 9; ++tap) {
            const int dr = tap / 3, dc = tap - dr * 3;
            const int rowb = ((wv + dr) * 58) << 6;
#pragma unroll
            for (int cg = 0; cg < 4; ++cg) {
                const bf16x8 Bv = *(const bf16x8*)((const char*)xb + rowb + addrc[cg][dc]);
#pragma unroll
                for (int mf = 0; mf < MFE; ++mf)
                    acc[mf][cg] = __builtin_amdgcn_mfma_f32_16x16x32_bf16(
                        A[mf][tap], Bv, acc[mf][cg], 0, 0, 0);
            }
        }
        if (q == nq - 1) {       // last q-phase of this stripe: store
            const int h = 4 * s + wv;
#pragma unroll
            for (int mf = 0; mf < MFE; ++mf)
#pragma unroll
                for (int reg = 0; reg < 4; ++reg) {
                    const int oc = ocv[mf][reg];
                    if (oc >= 0) {
                        float* op = out + ((size_t)(b * 256 + oc) * 56 + h) * 56;
#pragma unroll
                        for (int cg = 0; cg < 4; ++cg) {
                            const int col = cg * 16 + nn;
                            if (col < 56) op[col] = acc[mf][cg][reg];
                        }
                    }
                }
        }
        __builtin_amdgcn_sched_barrier(0);
        __builtin_amdgcn_s_barrier();
    }
}

__global__ __launch_bounds__(256, 2) void flgc_conv_r(const int* __restrict__ meta,
                                                      const unsigned short* __restrict__ wpack,
                                                      const unsigned short* __restrict__ xr,
                                                      float* __restrict__ out) {
    __shared__ __align__(16) unsigned short xbufA[11136];   // 22272 B
    __shared__ __align__(16) unsigned short xbufB[11136];   // 22272 B
    const int b = blockIdx.x, g = blockIdx.y, z = blockIdx.z;
    const int tid = threadIdx.x, lane = tid & 63, wv = tid >> 6;
    const int ccnt = meta[M_CCNT + g], fcnt = meta[M_FCNT + g];
    const int fbas = meta[M_FBASE + g], woffe = meta[M_WOFFE + g];
    int nq = (ccnt + 31) >> 5; if (nq > 2) nq = 2;
    const int mfall = (fcnt + 15) >> 4;
    if (mfall == 0) return;
    const int nn = lane & 15;

    for (int mf0 = 0; mf0 < mfall; mf0 += 3) {
        const int mfe = min(3, mfall - mf0);
        int ocv[3][4];
#pragma unroll
        for (int mf = 0; mf < 3; ++mf)
#pragma unroll
            for (int reg = 0; reg < 4; ++reg) {
                const int fl = (mf0 + mf) * 16 + (lane >> 4) * 4 + reg;
                ocv[mf][reg] = (mf < mfe && fl < fcnt)
                    ? meta[M_DEST + meta[M_FLIST + fbas + fl]] : -1;
            }
        if (nq == 0) {   // no input channels: outputs are zero
            const int ns = (z < 2) ? 4 : 3;
            for (int si = 0; si < ns; ++si) {
                const int h = 4 * (z + 4 * si) + wv;
#pragma unroll
                for (int mf = 0; mf < 3; ++mf)
#pragma unroll
                    for (int reg = 0; reg < 4; ++reg)
                        if (ocv[mf][reg] >= 0) {
                            float* op = out + ((size_t)(b * 256 + ocv[mf][reg]) * 56 + h) * 56;
#pragma unroll
                            for (int cg = 0; cg < 4; ++cg) {
                                const int col = cg * 16 + nn;
                                if (col < 56) op[col] = 0.f;
                            }
                        }
            }
            continue;
        }
        if (mfe == 3)      conv_pass<3>(wpack, xr, out, xbufA, xbufB, ocv, b, g, z, nq, mf0, mfall, woffe, lane, wv);
        else if (mfe == 2) conv_pass<2>(wpack, xr, out, xbufA, xbufB, ocv, b, g, z, nq, mf0, mfall, woffe, lane, wv);
        else               conv_pass<1>(wpack, xr, out, xbufA, xbufB, ocv, b, g, z, nq, mf0, mfall, woffe, lane, wv);
    }
}

// ---- fallback (small ws): round-2 direct-gather MFMA kernel, known-good.
__global__ __launch_bounds__(256, 2) void flgc_conv_mfma(const float* __restrict__ x,
                                                         const int* __restrict__ meta,
                                                         const unsigned short* __restrict__ wpack,
                                                         float* __restrict__ out) {
    __shared__ __align__(16) unsigned short xlds[10 * 4 * 64 * 8];
    __shared__ __align__(16) unsigned short wlds[4 * 9 * 512];
    const int g = blockIdx.z, b = blockIdx.y, h0 = blockIdx.x * 8;
    const int tid = threadIdx.x, lane = tid & 63, wv = tid >> 6;
    const int ccnt = meta[M_CCNT + g], fcnt = meta[M_FCNT + g];
    const int cbas = meta[M_CBASE + g], fbas = meta[M_FBASE + g];
    const int woffe = meta[M_WOFFE + g];
    const int nq = (ccnt + 31) >> 5, mfall = (fcnt + 15) >> 4;
    if (mfall == 0) return;
    const int n = lane & 15, kgl = lane >> 4;
    const int prow = 2 * wv + (n >> 3);
    const int pcol = n & 7;

    for (int mf0 = 0; mf0 < mfall; mf0 += 4) {
        const int mfe = min(4, mfall - mf0);
        f32x4 acc[4][7];
#pragma unroll
        for (int mf = 0; mf < 4; ++mf)
#pragma unroll
            for (int cg = 0; cg < 7; ++cg) acc[mf][cg] = (f32x4){0.f, 0.f, 0.f, 0.f};

        for (int q = 0; q < nq; ++q) {
            __syncthreads();
            for (int widx = wv; widx < mfe * 9; widx += 4) {
                const int mf = widx / 9, tap = widx - mf * 9;
                const unsigned short* src =
                    wpack + woffe + (((q * mfall) + mf0 + mf) * 9 + tap) * 512 + lane * 8;
                *(bf16x8*)&wlds[(mf * 9 + tap) * 512 + lane * 8] = *(const bf16x8*)src;
            }
            for (int i = tid; i < 80 * 64; i += 256) {
                const int colx = i & 63, t = i >> 6;
                const int rr = t >> 3, cq = t & 7;
                const int c0 = q * 32 + cq * 4;
                const int row = h0 + rr - 1, ic = colx - 1;
                float v0 = 0.f, v1 = 0.f, v2 = 0.f, v3 = 0.f;
                if ((unsigned)row < 56u && (unsigned)ic < 56u) {
                    const float* xp = x + (size_t)(b * 256) * 3136 + row * 56 + ic;
                    if (c0 + 0 < ccnt) v0 = xp[(size_t)meta[M_CLIST + cbas + c0 + 0] * 3136];
                    if (c0 + 1 < ccnt) v1 = xp[(size_t)meta[M_CLIST + cbas + c0 + 1] * 3136];
                    if (c0 + 2 < ccnt) v2 = xp[(size_t)meta[M_CLIST + cbas + c0 + 2] * 3136];
                    if (c0 + 3 < ccnt) v3 = xp[(size_t)meta[M_CLIST + cbas + c0 + 3] * 3136];
                }
                ushort4 pk = make_ushort4(f2bf(v0), f2bf(v1), f2bf(v2), f2bf(v3));
                *(ushort4*)&xlds[(((rr * 4 + (cq >> 1)) * 64 + colx) << 3) + ((cq & 1) << 2)] = pk;
            }
            __syncthreads();
#pragma unroll
            for (int tap = 0; tap < 9; ++tap) {
                const int dr = tap / 3, dcp = tap - dr * 3;
                bf16x8 A[4];
#pragma unroll
                for (int mf = 0; mf < 4; ++mf)
                    if (mf < mfe)
                        A[mf] = *(bf16x8*)&wlds[(mf * 9 + tap) * 512 + lane * 8];
                const int row_r = prow + dr;
                const int xbase = ((row_r * 4 + kgl) * 64) << 3;
#pragma unroll
                for (int cg = 0; cg < 7; ++cg) {
                    const int cc = cg * 8 + pcol + dcp;
                    const bf16x8 B = *(bf16x8*)&xlds[xbase + (cc << 3)];
#pragma unroll
                    for (int mf = 0; mf < 4; ++mf)
                        if (mf < mfe)
                            acc[mf][cg] = __builtin_amdgcn_mfma_f32_16x16x32_bf16(
                                A[mf], B, acc[mf][cg], 0, 0, 0);
                }
            }
        }
#pragma unroll
        for (int mf = 0; mf < 4; ++mf) {
            if (mf < mfe) {
#pragma unroll
                for (int reg = 0; reg < 4; ++reg) {
                    const int fl = (mf0 + mf) * 16 + (lane >> 4) * 4 + reg;
                    if (fl < fcnt) {
                        const int F  = meta[M_FLIST + fbas + fl];
                        const int oc = meta[M_DEST + F];
                        float* op = out + ((size_t)(b * 256 + oc) * 56 + (h0 + prow)) * 56 + pcol;
#pragma unroll
                        for (int cg = 0; cg < 7; ++cg)
                            op[cg * 8] = acc[mf][cg][reg];
                    }
                }
            }
        }
    }
}

extern "C" void kernel_launch(void* const* d_in, const int* in_sizes, int n_in,
                              void* d_out, int out_size, void* d_ws, size_t ws_size,
                              hipStream_t stream) {
    const float* x    = (const float*)d_in[0];   // [32,256,56,56]
    const float* conv = (const float*)d_in[1];   // [256,256,3,3]
    const float* S    = (const float*)d_in[2];   // [256,8]
    const float* T    = (const float*)d_in[3];   // [256,8]
    float* out = (float*)d_out;                  // [32,256,56,56]
    int* meta = (int*)d_ws;
    unsigned short* wpack = (unsigned short*)((char*)d_ws + WPACK_BYTE_OFF);
    unsigned short* xr    = (unsigned short*)((char*)d_ws + XR_BYTE_OFF);

    flgc_setup<<<1, 256, 0, stream>>>(S, T, meta);
    flgc_pack<<<256, 256, 0, stream>>>(conv, meta, wpack);

    const size_t need = (size_t)XR_BYTE_OFF + 16ull * SLOT_BYTES + 65536;
    if (ws_size >= need) {
        flgc_reorder<<<dim3(58, 32, 16), 256, 0, stream>>>(x, meta, xr);
        flgc_conv_r<<<dim3(32, 8, 4), 256, 0, stream>>>(meta, wpack, xr, out);
    } else {
        flgc_conv_mfma<<<dim3(7, 32, 8), 256, 0, stream>>>(x, meta, wpack, out);
    }
}

// Round 8
// 103.837 us; speedup vs baseline: 1.5131x; 1.0305x over previous
//
#include <hip/hip_runtime.h>

// ---------------- meta layout in d_ws, units of 4 bytes ----------------
#define M_SI    0      // f32[256] softmax max-prob per input channel
#define M_SO    256    // f32[256] per filter
#define M_CLIST 512    // i32[256] input channels, group-major stable
#define M_FLIST 768    // i32[256] filters, group-major stable (= perm)
#define M_DEST  1024   // i32[256] dest[f] = output channel for filter f
#define M_CBASE 1280   // i32[8]
#define M_FBASE 1288   // i32[8]
#define M_CCNT  1296   // i32[8]
#define M_FCNT  1304   // i32[8]
#define M_WOFFE 1312   // i32[9] element offsets into wpack, [8]=total
#define WPACK_BYTE_OFF 16384
#define XR_BYTE_OFF   (4u << 20)          // 4 MB
#define SLOT_ELEMS    3444736ull          // 32 b * 58*58 * 32 ch (bf16 elems)
#define SLOT_BYTES    (SLOT_ELEMS * 2ull)

typedef short bf16x8 __attribute__((ext_vector_type(8)));
typedef float f32x4  __attribute__((ext_vector_type(4)));

__device__ __forceinline__ unsigned short f2bf(float f) {
    unsigned u = __float_as_uint(f);
    u += 0x7fffu + ((u >> 16) & 1u);
    return (unsigned short)(u >> 16);
}

__device__ __forceinline__ void gl_lds16(const void* g, void* l) {
    __builtin_amdgcn_global_load_lds((const __attribute__((address_space(1))) unsigned int*)g,
                                     (__attribute__((address_space(3))) unsigned int*)l, 16, 0, 0);
}

__global__ __launch_bounds__(256) void flgc_setup(const float* __restrict__ S,
                                                  const float* __restrict__ T,
                                                  int* __restrict__ meta) {
    __shared__ float si[256], so[256];
    __shared__ int gin[256], gout[256];
    __shared__ int cnt_in[8], cnt_out[8], cb[8], fb[8];
    __shared__ int perm[256], destl[256];
    const int c = threadIdx.x;  // 0..255

    {   // softmax max-prob + argmax (first occurrence) for S row c
        float m = S[c * 8]; int am = 0;
        for (int k = 1; k < 8; ++k) { float v = S[c * 8 + k]; if (v > m) { m = v; am = k; } }
        float s = 0.f;
        for (int k = 0; k < 8; ++k) s += expf(S[c * 8 + k] - m);
        si[c] = 1.0f / s; gin[c] = am;
    }
    {
        float m = T[c * 8]; int am = 0;
        for (int k = 1; k < 8; ++k) { float v = T[c * 8 + k]; if (v > m) { m = v; am = k; } }
        float s = 0.f;
        for (int k = 0; k < 8; ++k) s += expf(T[c * 8 + k] - m);
        so[c] = 1.0f / s; gout[c] = am;
    }
    __syncthreads();
    const int g = gin[c], go = gout[c];
    int r1 = 0, r2 = 0;  // stable rank within group
    for (int i = 0; i < c; ++i) { r1 += (gin[i] == g); r2 += (gout[i] == go); }
    if (c < 8) {
        int n1 = 0, n2 = 0;
        for (int i = 0; i < 256; ++i) { n1 += (gin[i] == c); n2 += (gout[i] == c); }
        cnt_in[c] = n1; cnt_out[c] = n2;
    }
    __syncthreads();
    if (c == 0) {
        int a = 0, b = 0;
        for (int k = 0; k < 8; ++k) { cb[k] = a; a += cnt_in[k]; fb[k] = b; b += cnt_out[k]; }
    }
    __syncthreads();
    meta[M_CLIST + cb[g] + r1] = c;
    perm[fb[go] + r2] = c;               // = argsort(t stable)
    __syncthreads();
    const int ppc = perm[perm[c]];       // pp[j], j = c
    destl[ppc] = c;                      // dest[pp[j]] = j
    __syncthreads();
    ((float*)meta)[M_SI + c] = si[c];
    ((float*)meta)[M_SO + c] = so[c];
    meta[M_FLIST + c] = perm[c];
    meta[M_DEST + c]  = destl[c];
    if (c < 8) {
        meta[M_CBASE + c] = cb[c];
        meta[M_FBASE + c] = fb[c];
        meta[M_CCNT + c]  = cnt_in[c];
        meta[M_FCNT + c]  = cnt_out[c];
    }
    if (c == 0) {
        int a = 0;
        for (int k = 0; k < 8; ++k) {
            meta[M_WOFFE + k] = a;
            const int nq  = (cnt_in[k] + 31) >> 5;
            const int mfa = (cnt_out[k] + 15) >> 4;
            a += nq * mfa * 9 * 512;
        }
        meta[M_WOFFE + 8] = a;
    }
}

// wpack: per group, [q][mf][tap][lane 0..63][j 0..7] bf16 in exact A-fragment
// lane order for mfma_f32_16x16x32_bf16: f = mf*16 + (lane&15), c = q*32 + (lane>>4)*8 + j.
__global__ void flgc_pack(const float* __restrict__ conv, const int* __restrict__ meta,
                          unsigned short* __restrict__ wpack) {
    const float* si = (const float*)meta + M_SI;
    const float* so = (const float*)meta + M_SO;
    const int total = meta[M_WOFFE + 8];
    for (int idx = blockIdx.x * blockDim.x + threadIdx.x; idx < total;
         idx += gridDim.x * blockDim.x) {
        int gg = 0;
        while (gg < 7 && idx >= meta[M_WOFFE + gg + 1]) ++gg;
        const int local = idx - meta[M_WOFFE + gg];
        const int fcnt = meta[M_FCNT + gg], ccnt = meta[M_CCNT + gg];
        const int mfall = (fcnt + 15) >> 4;
        const int fragidx = local >> 9, e = local & 511;
        const int lane = e >> 3, j = e & 7;
        const int tap = fragidx % 9, t2 = fragidx / 9;
        const int mf = t2 % mfall, q = t2 / mfall;
        const int fl = mf * 16 + (lane & 15);
        const int cl = q * 32 + (lane >> 4) * 8 + j;
        float v = 0.f;
        if (fl < fcnt && cl < ccnt) {
            const int F  = meta[M_FLIST + meta[M_FBASE + gg] + fl];
            const int CH = meta[M_CLIST + meta[M_CBASE + gg] + cl];
            v = conv[(F * 256 + CH) * 9 + tap] * si[CH] * so[F];
        }
        wpack[idx] = f2bf(v);
    }
}

// ---- reorder x -> xr[g*2+q][b][row 0..57][col 0..57][chunk-swizzled cl] bf16.
// Wide-load version: 4 rows/block, float4 gathers (16B/lane, 224B runs/channel),
// fp32 LDS staging, same XOR chunk swizzle on output as before.
__global__ __launch_bounds__(256) void flgc_reorder(const float* __restrict__ x,
                                                    const int* __restrict__ meta,
                                                    unsigned short* __restrict__ xr) {
    __shared__ float lds[4][32][60];    // 60-pad: aligned b128 writes, spread banks
    const int r0 = blockIdx.x * 4;      // xr rows r0..r0+3 (58 total)
    const int b = blockIdx.y;
    const int slot = blockIdx.z;        // g*2+q
    const int g = slot >> 1, q = slot & 1;
    const int ccnt = meta[M_CCNT + g];
    int nq = (ccnt + 31) >> 5; if (nq > 2) nq = 2;
    if (q >= nq) return;
    const int cbas = meta[M_CBASE + g];
    const int tid = threadIdx.x;
    const int q4 = tid & 15;            // col quad: x cols 4q4..4q4+3 (q4<14)
    const int ch16 = tid >> 4;          // 0..15; channels it*16+ch16

    int chn[2];
#pragma unroll
    for (int it = 0; it < 2; ++it) {
        const int cgl = q * 32 + it * 16 + ch16;
        chn[it] = (cgl < ccnt) ? meta[M_CLIST + cbas + cgl] : -1;
    }
    float4 v[4][2];
#pragma unroll
    for (int rr = 0; rr < 4; ++rr)
#pragma unroll
        for (int it = 0; it < 2; ++it)
            v[rr][it] = make_float4(0.f, 0.f, 0.f, 0.f);
    // 8 independent float4 loads (guards wave-uniform except q4<14)
#pragma unroll
    for (int rr = 0; rr < 4; ++rr) {
        const int row = r0 + rr - 1;
        if ((unsigned)row < 56u && q4 < 14) {
            const float* xb = x + (size_t)b * 256 * 3136 + row * 56 + q4 * 4;
#pragma unroll
            for (int it = 0; it < 2; ++it)
                if (chn[it] >= 0)
                    v[rr][it] = *(const float4*)(xb + (size_t)chn[it] * 3136);
        }
    }
#pragma unroll
    for (int rr = 0; rr < 4; ++rr)
#pragma unroll
        for (int it = 0; it < 2; ++it)
            if (q4 < 14)
                *(float4*)&lds[rr][it * 16 + ch16][q4 * 4] = v[rr][it];
    __syncthreads();

    unsigned short* dstbase = xr + (size_t)(slot * 32 + b) * 107648ull;
    for (int i = tid; i < 4 * 464; i += 256) {
        const int rr = i / 464;
        const int rem = i - rr * 464;
        const int r = r0 + rr;
        if (r < 58) {
            const int col = rem >> 3, c8 = rem & 7;
            const int chunk = c8 >> 1, lo = (c8 & 1) * 4;
            const int cl4 = chunk * 8 + lo;
            const int icol = col - 1;
            ushort4 pk;
            if ((unsigned)icol < 56u)
                pk = make_ushort4(f2bf(lds[rr][cl4 + 0][icol]), f2bf(lds[rr][cl4 + 1][icol]),
                                  f2bf(lds[rr][cl4 + 2][icol]), f2bf(lds[rr][cl4 + 3][icol]));
            else
                pk = make_ushort4(0, 0, 0, 0);
            const int schunk = chunk ^ ((col >> 1) & 3);
            *(ushort4*)&dstbase[(size_t)r * 1856 + col * 32 + schunk * 8 + lo] = pk;
        }
    }
}

// ============ pipelined conv, per-phase A loads ============
// Block=(b,g,z), 4 waves, 4-row stripes s = z+4k. All mf (<=3) per staged tile.
// Per phase: batch-load A frags (global, L2-hot) -> sched fence -> issue next
// x tile (6 gl_lds16/wave) -> vmcnt(6) [prev tile + A drained, next in flight]
// -> barrier -> 36*MFE MFMA -> store (last q) -> barrier.
template <int MFE>
__device__ __forceinline__ void conv_pass(
    const unsigned short* __restrict__ wpack, const unsigned short* __restrict__ xr,
    float* __restrict__ out, unsigned short* xbufA, unsigned short* xbufB,
    const int (&ocv)[3][4], int b, int g, int z, int nq, int mf0, int mfall, int woffe,
    int lane, int wv) {
    const int nn = lane & 15, kg = lane >> 4;
    // ---- precomputed B column byte-offsets (phase-invariant) ----
    int addrc[4][3];
#pragma unroll
    for (int cg = 0; cg < 4; ++cg)
#pragma unroll
        for (int dc = 0; dc < 3; ++dc) {
            int ccol = cg * 16 + nn + dc; if (ccol > 57) ccol = 57;
            addrc[cg][dc] = (ccol << 6) + ((kg ^ ((ccol >> 1) & 3)) << 4);
        }
    const int ns = (z < 2) ? 4 : 3;
    const int P = ns * nq;
    const int base = wv * 348;
    // ---- prologue: stage tile for phase 0 (s=z, q=0) into xbufA ----
    {
        const char* src = (const char*)(xr + (size_t)((g * 2) * 32 + b) * 107648ull
                                        + (size_t)(4 * z) * 1856);
        char* dstb = (char*)xbufA;
#pragma unroll
        for (int j = 0; j < 5; ++j)
            gl_lds16(src + (size_t)(base + j * 64 + lane) * 16, dstb + (base + j * 64) * 16);
        if (lane < 28)
            gl_lds16(src + (size_t)(base + 320 + lane) * 16, dstb + (base + 320) * 16);
    }
    f32x4 acc[MFE][4];
    for (int p = 0; p < P; ++p) {
        const int q = (nq == 2) ? (p & 1) : 0;
        const int s = z + 4 * ((nq == 2) ? (p >> 1) : p);
        // ---- A fragments for THIS phase: batched independent global loads ----
        bf16x8 A[MFE][9];
        {
            const unsigned short* ap =
                wpack + woffe + ((size_t)(q * mfall + mf0) * 9) * 512 + lane * 8;
#pragma unroll
            for (int mf = 0; mf < MFE; ++mf)
#pragma unroll
                for (int tap = 0; tap < 9; ++tap)
                    A[mf][tap] = *(const bf16x8*)(ap + (size_t)(mf * 9 + tap) * 512);
        }
        __builtin_amdgcn_sched_barrier(0);   // keep A issues ahead of staging issues
        if (p + 1 < P) {
            const int pn = p + 1;
            const int qp = (nq == 2) ? (pn & 1) : 0;
            const int sp = z + 4 * ((nq == 2) ? (pn >> 1) : pn);
            const char* src = (const char*)(xr + (size_t)((g * 2 + qp) * 32 + b) * 107648ull
                                            + (size_t)(4 * sp) * 1856);
            char* dstb = (char*)((pn & 1) ? xbufB : xbufA);
#pragma unroll
            for (int j = 0; j < 5; ++j)
                gl_lds16(src + (size_t)(base + j * 64 + lane) * 16, dstb + (base + j * 64) * 16);
            if (lane < 28)
                gl_lds16(src + (size_t)(base + 320 + lane) * 16, dstb + (base + 320) * 16);
            asm volatile("s_waitcnt vmcnt(6)" ::: "memory");   // prev tile + A drained
        } else {
            asm volatile("s_waitcnt vmcnt(0)" ::: "memory");
        }
        __builtin_amdgcn_s_barrier();
        __builtin_amdgcn_sched_barrier(0);
        const unsigned short* xb = (p & 1) ? xbufB : xbufA;
        if (q == 0) {
#pragma unroll
            for (int mf = 0; mf < MFE; ++mf)
#pragma unroll
                for (int cg = 0; cg < 4; ++cg) acc[mf][cg] = (f32x4){0.f, 0.f, 0.f, 0.f};
        }
#pragma unroll
        for (int tap = 0; tap < 9; ++tap) {
            const int dr = tap / 3, dc = tap - dr * 3;
            const int rowb = ((wv + dr) * 58) << 6;
#pragma unroll
            for (int cg = 0; cg < 4; ++cg) {
                const bf16x8 Bv = *(const bf16x8*)((const char*)xb + rowb + addrc[cg][dc]);
#pragma unroll
                for (int mf = 0; mf < MFE; ++mf)
                    acc[mf][cg] = __builtin_amdgcn_mfma_f32_16x16x32_bf16(
                        A[mf][tap], Bv, acc[mf][cg], 0, 0, 0);
            }
        }
        if (q == nq - 1) {       // last q-phase of this stripe: store
            const int h = 4 * s + wv;
#pragma unroll
            for (int mf = 0; mf < MFE; ++mf)
#pragma unroll
                for (int reg = 0; reg < 4; ++reg) {
                    const int oc = ocv[mf][reg];
                    if (oc >= 0) {
                        float* op = out + ((size_t)(b * 256 + oc) * 56 + h) * 56;
#pragma unroll
                        for (int cg = 0; cg < 4; ++cg) {
                            const int col = cg * 16 + nn;
                            if (col < 56) op[col] = acc[mf][cg][reg];
                        }
                    }
                }
        }
        __builtin_amdgcn_sched_barrier(0);
        __builtin_amdgcn_s_barrier();
    }
}

__global__ __launch_bounds__(256, 2) void flgc_conv_r(const int* __restrict__ meta,
                                                      const unsigned short* __restrict__ wpack,
                                                      const unsigned short* __restrict__ xr,
                                                      float* __restrict__ out) {
    __shared__ __align__(16) unsigned short xbufA[11136];   // 22272 B
    __shared__ __align__(16) unsigned short xbufB[11136];   // 22272 B
    const int b = blockIdx.x, g = blockIdx.y, z = blockIdx.z;
    const int tid = threadIdx.x, lane = tid & 63, wv = tid >> 6;
    const int ccnt = meta[M_CCNT + g], fcnt = meta[M_FCNT + g];
    const int fbas = meta[M_FBASE + g], woffe = meta[M_WOFFE + g];
    int nq = (ccnt + 31) >> 5; if (nq > 2) nq = 2;
    const int mfall = (fcnt + 15) >> 4;
    if (mfall == 0) return;
    const int nn = lane & 15;

    for (int mf0 = 0; mf0 < mfall; mf0 += 3) {
        const int mfe = min(3, mfall - mf0);
        int ocv[3][4];
#pragma unroll
        for (int mf = 0; mf < 3; ++mf)
#pragma unroll
            for (int reg = 0; reg < 4; ++reg) {
                const int fl = (mf0 + mf) * 16 + (lane >> 4) * 4 + reg;
                ocv[mf][reg] = (mf < mfe && fl < fcnt)
                    ? meta[M_DEST + meta[M_FLIST + fbas + fl]] : -1;
            }
        if (nq == 0) {   // no input channels: outputs are zero
            const int ns = (z < 2) ? 4 : 3;
            for (int si = 0; si < ns; ++si) {
                const int h = 4 * (z + 4 * si) + wv;
#pragma unroll
                for (int mf = 0; mf < 3; ++mf)
#pragma unroll
                    for (int reg = 0; reg < 4; ++reg)
                        if (ocv[mf][reg] >= 0) {
                            float* op = out + ((size_t)(b * 256 + ocv[mf][reg]) * 56 + h) * 56;
#pragma unroll
                            for (int cg = 0; cg < 4; ++cg) {
                                const int col = cg * 16 + nn;
                                if (col < 56) op[col] = 0.f;
                            }
                        }
            }
            continue;
        }
        if (mfe == 3)      conv_pass<3>(wpack, xr, out, xbufA, xbufB, ocv, b, g, z, nq, mf0, mfall, woffe, lane, wv);
        else if (mfe == 2) conv_pass<2>(wpack, xr, out, xbufA, xbufB, ocv, b, g, z, nq, mf0, mfall, woffe, lane, wv);
        else               conv_pass<1>(wpack, xr, out, xbufA, xbufB, ocv, b, g, z, nq, mf0, mfall, woffe, lane, wv);
    }
}

// ---- fallback (small ws): round-2 direct-gather MFMA kernel, known-good.
__global__ __launch_bounds__(256, 2) void flgc_conv_mfma(const float* __restrict__ x,
                                                         const int* __restrict__ meta,
                                                         const unsigned short* __restrict__ wpack,
                                                         float* __restrict__ out) {
    __shared__ __align__(16) unsigned short xlds[10 * 4 * 64 * 8];
    __shared__ __align__(16) unsigned short wlds[4 * 9 * 512];
    const int g = blockIdx.z, b = blockIdx.y, h0 = blockIdx.x * 8;
    const int tid = threadIdx.x, lane = tid & 63, wv = tid >> 6;
    const int ccnt = meta[M_CCNT + g], fcnt = meta[M_FCNT + g];
    const int cbas = meta[M_CBASE + g], fbas = meta[M_FBASE + g];
    const int woffe = meta[M_WOFFE + g];
    const int nq = (ccnt + 31) >> 5, mfall = (fcnt + 15) >> 4;
    if (mfall == 0) return;
    const int n = lane & 15, kgl = lane >> 4;
    const int prow = 2 * wv + (n >> 3);
    const int pcol = n & 7;

    for (int mf0 = 0; mf0 < mfall; mf0 += 4) {
        const int mfe = min(4, mfall - mf0);
        f32x4 acc[4][7];
#pragma unroll
        for (int mf = 0; mf < 4; ++mf)
#pragma unroll
            for (int cg = 0; cg < 7; ++cg) acc[mf][cg] = (f32x4){0.f, 0.f, 0.f, 0.f};

        for (int q = 0; q < nq; ++q) {
            __syncthreads();
            for (int widx = wv; widx < mfe * 9; widx += 4) {
                const int mf = widx / 9, tap = widx - mf * 9;
                const unsigned short* src =
                    wpack + woffe + (((q * mfall) + mf0 + mf) * 9 + tap) * 512 + lane * 8;
                *(bf16x8*)&wlds[(mf * 9 + tap) * 512 + lane * 8] = *(const bf16x8*)src;
            }
            for (int i = tid; i < 80 * 64; i += 256) {
                const int colx = i & 63, t = i >> 6;
                const int rr = t >> 3, cq = t & 7;
                const int c0 = q * 32 + cq * 4;
                const int row = h0 + rr - 1, ic = colx - 1;
                float v0 = 0.f, v1 = 0.f, v2 = 0.f, v3 = 0.f;
                if ((unsigned)row < 56u && (unsigned)ic < 56u) {
                    const float* xp = x + (size_t)(b * 256) * 3136 + row * 56 + ic;
                    if (c0 + 0 < ccnt) v0 = xp[(size_t)meta[M_CLIST + cbas + c0 + 0] * 3136];
                    if (c0 + 1 < ccnt) v1 = xp[(size_t)meta[M_CLIST + cbas + c0 + 1] * 3136];
                    if (c0 + 2 < ccnt) v2 = xp[(size_t)meta[M_CLIST + cbas + c0 + 2] * 3136];
                    if (c0 + 3 < ccnt) v3 = xp[(size_t)meta[M_CLIST + cbas + c0 + 3] * 3136];
                }
                ushort4 pk = make_ushort4(f2bf(v0), f2bf(v1), f2bf(v2), f2bf(v3));
                *(ushort4*)&xlds[(((rr * 4 + (cq >> 1)) * 64 + colx) << 3) + ((cq & 1) << 2)] = pk;
            }
            __syncthreads();
#pragma unroll
            for (int tap = 0; tap < 9; ++tap) {
                const int dr = tap / 3, dcp = tap - dr * 3;
                bf16x8 A[4];
#pragma unroll
                for (int mf = 0; mf < 4; ++mf)
                    if (mf < mfe)
                        A[mf] = *(bf16x8*)&wlds[(mf * 9 + tap) * 512 + lane * 8];
                const int row_r = prow + dr;
                const int xbase = ((row_r * 4 + kgl) * 64) << 3;
#pragma unroll
                for (int cg = 0; cg < 7; ++cg) {
                    const int cc = cg * 8 + pcol + dcp;
                    const bf16x8 B = *(bf16x8*)&xlds[xbase + (cc << 3)];
#pragma unroll
                    for (int mf = 0; mf < 4; ++mf)
                        if (mf < mfe)
                            acc[mf][cg] = __builtin_amdgcn_mfma_f32_16x16x32_bf16(
                                A[mf], B, acc[mf][cg], 0, 0, 0);
                }
            }
        }
#pragma unroll
        for (int mf = 0; mf < 4; ++mf) {
            if (mf < mfe) {
#pragma unroll
                for (int reg = 0; reg < 4; ++reg) {
                    const int fl = (mf0 + mf) * 16 + (lane >> 4) * 4 + reg;
                    if (fl < fcnt) {
                        const int F  = meta[M_FLIST + fbas + fl];
                        const int oc = meta[M_DEST + F];
                        float* op = out + ((size_t)(b * 256 + oc) * 56 + (h0 + prow)) * 56 + pcol;
#pragma unroll
                        for (int cg = 0; cg < 7; ++cg)
                            op[cg * 8] = acc[mf][cg][reg];
                    }
                }
            }
        }
    }
}

extern "C" void kernel_launch(void* const* d_in, const int* in_sizes, int n_in,
                              void* d_out, int out_size, void* d_ws, size_t ws_size,
                              hipStream_t stream) {
    const float* x    = (const float*)d_in[0];   // [32,256,56,56]
    const float* conv = (const float*)d_in[1];   // [256,256,3,3]
    const float* S    = (const float*)d_in[2];   // [256,8]
    const float* T    = (const float*)d_in[3];   // [256,8]
    float* out = (float*)d_out;                  // [32,256,56,56]
    int* meta = (int*)d_ws;
    unsigned short* wpack = (unsigned short*)((char*)d_ws + WPACK_BYTE_OFF);
    unsigned short* xr    = (unsigned short*)((char*)d_ws + XR_BYTE_OFF);

    flgc_setup<<<1, 256, 0, stream>>>(S, T, meta);
    flgc_pack<<<256, 256, 0, stream>>>(conv, meta, wpack);

    const size_t need = (size_t)XR_BYTE_OFF + 16ull * SLOT_BYTES + 65536;
    if (ws_size >= need) {
        flgc_reorder<<<dim3(15, 32, 16), 256, 0, stream>>>(x, meta, xr);
        flgc_conv_r<<<dim3(32, 8, 4), 256, 0, stream>>>(meta, wpack, xr, out);
    } else {
        flgc_conv_mfma<<<dim3(7, 32, 8), 256, 0, stream>>>(x, meta, wpack, out);
    }
}